// Round 2
// baseline (419.081 us; speedup 1.0000x reference)
//
#include <hip/hip_runtime.h>
#include <math.h>

#define DELTA_ 1e-6f
#define IFACE_ 471
#define XI_STRIDE 480

// workspace offsets (in floats)
#define OFF_XI    0            // 32*480
#define OFF_RKN   15360        // 32*4*64 normalized read keys
#define OFF_RS    23552        // 32*4 read strengths (softplus)
#define OFF_ER    23680        // 32*64 erase (sigmoid)
#define OFF_WV    25728        // 32*64 write vec (tanh)
#define OFF_RM    27776        // 32*12 read modes (softmaxed)
#define OFF_WW    28160        // 32*1024 write weights
#define OFF_WWRW  60928        // 32*4*1024 ww[j]*rw[r,j]
#define OFF_PRD   192000       // 32*4 sum_j p[j] rw[r,j]
#define OFF_WRD   192128       // 32*4 sum_j ww[j] rw[r,j]
#define OFF_INVN  192256       // 32*1024 1/(||new_mem row||+DELTA)
#define OFF_NM    225024       // 32*1024*64 new memory
#define OFF_RA    2322176      // 32*4*1024  sum_j L[i,j] rw[r,j]
#define OFF_RB    2453248      // 32*4*1024  sum_j L[i,j] wwrw[r,j]
#define OFF_SAP   2584320      // 32*8*4*1024 col-sum partials (rw)
#define OFF_SBP   3632896      // 32*8*4*1024 col-sum partials (wwrw)
#define OFF_NRW   4681472      // 32*4*1024 new read weights
// total 4812544 floats = 18.4 MB

__device__ __forceinline__ float sigm_(float x){ return 1.f/(1.f+expf(-x)); }
__device__ __forceinline__ float softp_(float x){ return fmaxf(x,0.f)+log1pf(expf(-fabsf(x))); }
__device__ __forceinline__ float dot4_(float4 a, float4 b){ return a.x*b.x+a.y*b.y+a.z*b.z+a.w*b.w; }

// ---------------- K1: xi = x @ W_if + b_if ----------------
__global__ __launch_bounds__(256) void k_xi(const float* __restrict__ x,
    const float* __restrict__ W, const float* __restrict__ bias,
    float* __restrict__ xi) {
  int b = blockIdx.x;
  int j = blockIdx.y*256 + threadIdx.x;
  __shared__ float sx[1024];
  for (int k = threadIdx.x; k < 1024; k += 256) sx[k] = x[b*1024+k];
  __syncthreads();
  if (j < IFACE_) {
    float a0=0.f,a1=0.f,a2=0.f,a3=0.f;
    for (int k=0;k<1024;k+=4) {
      a0 += sx[k+0]*W[(size_t)(k+0)*IFACE_+j];
      a1 += sx[k+1]*W[(size_t)(k+1)*IFACE_+j];
      a2 += sx[k+2]*W[(size_t)(k+2)*IFACE_+j];
      a3 += sx[k+3]*W[(size_t)(k+3)*IFACE_+j];
    }
    xi[b*XI_STRIDE + j] = a0+a1+a2+a3 + bias[j];
  }
}

// ---------------- K2: per-batch small work: activations, wcw, usage, sort/alloc, ww ----------------
__global__ __launch_bounds__(256) void k_batch(
    const float* __restrict__ xi, const float* __restrict__ memory,
    const float* __restrict__ usage, const float* __restrict__ read_w,
    const float* __restrict__ write_w, const float* __restrict__ precedence,
    float* __restrict__ rkn, float* __restrict__ rs, float* __restrict__ er,
    float* __restrict__ wv, float* __restrict__ rm, float* __restrict__ ww_out,
    float* __restrict__ wwrw, float* __restrict__ prd, float* __restrict__ wrd) {
  int b = blockIdx.x; int t = threadIdx.x;
  int lane = t & 63; int wave = t >> 6;
  __shared__ float s_act[472];
  __shared__ __align__(16) float s_key[64];
  __shared__ float s_wcw[1024];
  __shared__ unsigned long long s_k64[1024];
  __shared__ float s_ps[1024];
  __shared__ float s_alloc[1024];
  __shared__ float s_red[32];
  __shared__ float s_bc[2];

  // 1) activations -- FIX: strided loop, block has only 256 threads for 471 slots
  for (int q = t; q < IFACE_; q += 256) {
    float v = xi[b*XI_STRIDE+q];
    float a;
    if      (q < 256) a = tanhf(v);    // read keys
    else if (q < 260) a = softp_(v);   // read strengths
    else if (q < 324) a = tanhf(v);    // write key
    else if (q < 325) a = softp_(v);   // write strength
    else if (q < 389) a = sigm_(v);    // erase
    else if (q < 453) a = tanhf(v);    // write vector
    else if (q < 459) a = sigm_(v);    // fg(4), ag, wg
    else              a = v;           // read modes raw
    s_act[q] = a;
  }
  __syncthreads();
  // read-modes softmax
  if (t < 4) {
    float m0=s_act[459+3*t], m1=s_act[460+3*t], m2=s_act[461+3*t];
    float mx=fmaxf(m0,fmaxf(m1,m2));
    float e0=expf(m0-mx), e1=expf(m1-mx), e2=expf(m2-mx);
    float s=e0+e1+e2;
    rm[b*12+3*t+0]=e0/s; rm[b*12+3*t+1]=e1/s; rm[b*12+3*t+2]=e2/s;
  }
  if (t < 64) { er[b*64+t]=s_act[325+t]; wv[b*64+t]=s_act[389+t]; }
  // normalize read keys (wave r handles key r)
  {
    int r = wave;
    float v = s_act[r*64+lane];
    float ss = v*v;
    for (int off=32; off; off>>=1) ss += __shfl_xor(ss, off);
    rkn[((size_t)b*4+r)*64+lane] = v / (sqrtf(ss)+DELTA_);
    if (lane==0) rs[b*4+r] = s_act[256+r];
  }
  // normalize write key (wave 0)
  if (wave==0) {
    float v = s_act[260+lane];
    float ss=v*v;
    for (int off=32; off; off>>=1) ss += __shfl_xor(ss, off);
    s_key[lane] = v/(sqrtf(ss)+DELTA_);
  }
  __syncthreads();
  float wstr = s_act[324], agv = s_act[457], wgv = s_act[458];

  // 2) write content weights: cosine sim + softmax over N (old memory)
  for (int n=t; n<1024; n+=256) {
    const float4* row = (const float4*)(memory + ((size_t)b*1024+n)*64);
    float dot=0.f, nn2=0.f;
    #pragma unroll
    for (int w4=0; w4<16; ++w4) {
      float4 m4 = row[w4];
      float4 k4 = ((const float4*)s_key)[w4];
      dot += dot4_(m4,k4);
      nn2 += dot4_(m4,m4);
    }
    s_wcw[n] = dot/(sqrtf(nn2)+DELTA_) * wstr;
  }
  __syncthreads();
  { // softmax over s_wcw
    float lm=-1e30f;
    for (int n=t;n<1024;n+=256) lm=fmaxf(lm,s_wcw[n]);
    for (int off=32;off;off>>=1) lm=fmaxf(lm,__shfl_xor(lm,off));
    if (lane==0) s_red[wave]=lm;
    __syncthreads();
    if (t==0) s_bc[0]=fmaxf(fmaxf(s_red[0],s_red[1]),fmaxf(s_red[2],s_red[3]));
    __syncthreads();
    float mx=s_bc[0], ls=0.f;
    for (int n=t;n<1024;n+=256){ float e=expf(s_wcw[n]-mx); s_wcw[n]=e; ls+=e; }
    for (int off=32;off;off>>=1) ls+=__shfl_xor(ls,off);
    if (lane==0) s_red[wave]=ls;
    __syncthreads();
    if (t==0) s_bc[1]=s_red[0]+s_red[1]+s_red[2]+s_red[3];
    __syncthreads();
    float inv=1.f/s_bc[1];
    for (int n=t;n<1024;n+=256) s_wcw[n]*=inv;
  }
  __syncthreads();

  // 3) usage -> sort keys
  for (int n=t; n<1024; n+=256) {
    float us = usage[b*1024+n];
    float wwi = write_w[b*1024+n];
    float u = us + (1.f-us)*wwi;
    float psi = 1.f;
    #pragma unroll
    for (int r=0;r<4;++r) psi *= (1.f - s_act[453+r]*read_w[((size_t)b*4+r)*1024+n]);
    u *= psi;
    u = DELTA_ + (1.f-DELTA_)*u;
    unsigned int ub = __float_as_uint(u);  // u > 0 -> bits monotone
    s_k64[n] = ((unsigned long long)ub<<32) | (unsigned int)n;
  }

  // 4) bitonic sort ascending (stable via idx in low bits)
  for (int k=2; k<=1024; k<<=1) {
    for (int j=k>>1; j>0; j>>=1) {
      __syncthreads();
      for (int idx=t; idx<1024; idx+=256) {
        int partner = idx ^ j;
        if (partner > idx) {
          unsigned long long a=s_k64[idx], c=s_k64[partner];
          bool asc = ((idx & k) == 0);
          bool sw = asc ? (a > c) : (a < c);
          if (sw) { s_k64[idx]=c; s_k64[partner]=a; }
        }
      }
    }
  }
  __syncthreads();

  // 5) exclusive cumprod (Hillis-Steele inclusive, shifted read)
  for (int n=t;n<1024;n+=256) s_ps[n] = __uint_as_float((unsigned int)(s_k64[n]>>32));
  __syncthreads();
  for (int off=1; off<1024; off<<=1) {
    float tmp[4];
    #pragma unroll
    for (int m=0;m<4;++m){ int n=t+256*m; tmp[m] = (n>=off)? s_ps[n-off] : 1.f; }
    __syncthreads();
    #pragma unroll
    for (int m=0;m<4;++m){ int n=t+256*m; s_ps[n] *= tmp[m]; }
    __syncthreads();
  }
  // scatter allocation back to original order
  for (int n=t;n<1024;n+=256) {
    unsigned long long kv = s_k64[n];
    float su = __uint_as_float((unsigned int)(kv>>32));
    int oi = (int)(kv & 0xffffffffu);
    float prod = (n==0)?1.f:s_ps[n-1];
    s_alloc[oi] = (1.f-su)*prod;
  }
  __syncthreads();

  // 6) ww, wwrw, dot products
  float pp[4]={0,0,0,0}, wp[4]={0,0,0,0};
  for (int n=t;n<1024;n+=256) {
    float w_ = wgv*(agv*s_alloc[n] + (1.f-agv)*s_wcw[n]);
    ww_out[b*1024+n]=w_;
    float pn = precedence[b*1024+n];
    #pragma unroll
    for (int r=0;r<4;++r){
      float rwv = read_w[((size_t)b*4+r)*1024+n];
      wwrw[((size_t)b*4+r)*1024+n] = w_*rwv;
      pp[r] += pn*rwv;
      wp[r] += w_*rwv;
    }
  }
  #pragma unroll
  for (int r=0;r<4;++r){
    for (int off=32;off;off>>=1){ pp[r]+=__shfl_xor(pp[r],off); wp[r]+=__shfl_xor(wp[r],off); }
  }
  if (lane==0){
    #pragma unroll
    for (int r=0;r<4;++r){ s_red[wave*8+r]=pp[r]; s_red[wave*8+4+r]=wp[r]; }
  }
  __syncthreads();
  if (t<4)              prd[b*4+t]   = s_red[t]+s_red[8+t]+s_red[16+t]+s_red[24+t];
  else if (t<8){ int r=t-4; wrd[b*4+r] = s_red[4+r]+s_red[12+r]+s_red[20+r]+s_red[28+r]; }
}

// ---------------- K3: new memory + row inverse norms ----------------
__global__ __launch_bounds__(256) void k_newmem(const float* __restrict__ memory,
    const float* __restrict__ ww, const float* __restrict__ er,
    const float* __restrict__ wv, float* __restrict__ newmem, float* __restrict__ invn) {
  int b = blockIdx.x;
  int n = blockIdx.y*4 + (threadIdx.x>>6);
  int w = threadIdx.x & 63;
  float wn = ww[b*1024+n];
  float e = er[b*64+w], v = wv[b*64+w];
  size_t idx = ((size_t)b*1024+n)*64+w;
  float m = memory[idx];
  float nv = m*(1.f - wn*e) + wn*v;
  newmem[idx] = nv;
  float ss=nv*nv;
  for (int off=32;off;off>>=1) ss+=__shfl_xor(ss,off);
  if (w==0) invn[b*1024+n] = 1.f/(sqrtf(ss)+DELTA_);
}

// ---------------- K4a: row dots RA/RB (fwd path) ----------------
__global__ __launch_bounds__(256) void k_fwd(const float* __restrict__ L,
    const float* __restrict__ read_w, const float* __restrict__ wwrw,
    float* __restrict__ RA, float* __restrict__ RB) {
  int b = blockIdx.x;
  int i0 = blockIdx.y*32;
  __shared__ __align__(16) float4 s_rw[4][256];
  __shared__ __align__(16) float4 s_wr[4][256];
  for (int q=threadIdx.x; q<1024; q+=256) {
    int r=q>>8, c4=q&255;
    s_rw[r][c4] = ((const float4*)(read_w + ((size_t)b*4+r)*1024))[c4];
    s_wr[r][c4] = ((const float4*)(wwrw   + ((size_t)b*4+r)*1024))[c4];
  }
  __syncthreads();
  int wave=threadIdx.x>>6, lane=threadIdx.x&63;
  for (int qg=0; qg<2; ++qg) {
    int ib = i0 + wave*8 + qg*4;
    const float4* r0 = (const float4*)(L + ((size_t)b*1024 + ib+0)*1024);
    const float4* r1 = (const float4*)(L + ((size_t)b*1024 + ib+1)*1024);
    const float4* r2 = (const float4*)(L + ((size_t)b*1024 + ib+2)*1024);
    const float4* r3 = (const float4*)(L + ((size_t)b*1024 + ib+3)*1024);
    float acc[4][8];
    #pragma unroll
    for (int q=0;q<4;++q) for (int d=0;d<8;++d) acc[q][d]=0.f;
    #pragma unroll
    for (int m=0;m<4;++m){
      int c4 = lane + (m<<6);
      float4 l0=r0[c4], l1=r1[c4], l2=r2[c4], l3=r3[c4];
      #pragma unroll
      for (int r=0;r<4;++r){
        float4 rv=s_rw[r][c4], wv4=s_wr[r][c4];
        acc[0][r]+=dot4_(l0,rv); acc[0][r+4]+=dot4_(l0,wv4);
        acc[1][r]+=dot4_(l1,rv); acc[1][r+4]+=dot4_(l1,wv4);
        acc[2][r]+=dot4_(l2,rv); acc[2][r+4]+=dot4_(l2,wv4);
        acc[3][r]+=dot4_(l3,rv); acc[3][r+4]+=dot4_(l3,wv4);
      }
    }
    #pragma unroll
    for (int q=0;q<4;++q){
      #pragma unroll
      for (int d=0;d<8;++d){
        float v=acc[q][d];
        for (int off=32;off;off>>=1) v+=__shfl_xor(v,off);
        if (lane==0){
          int i = ib+q;
          if (d<4) RA[((size_t)b*4+d)*1024+i]=v;
          else     RB[((size_t)b*4+(d-4))*1024+i]=v;
        }
      }
    }
  }
}

// ---------------- K4b: column-sum partials SA/SB (bwd path) ----------------
__global__ __launch_bounds__(256) void k_bwd(const float* __restrict__ L,
    const float* __restrict__ read_w, const float* __restrict__ wwrw,
    float* __restrict__ SAp, float* __restrict__ SBp) {
  int b = blockIdx.x;
  int rc = blockIdx.y;   // 0..7 row chunks of 128
  int cc = blockIdx.z;   // 0..3 col chunks of 256
  int i0 = rc*128, c = cc*256 + threadIdx.x;
  __shared__ float s_rw[4][128], s_wr[4][128];
  for (int q=threadIdx.x;q<512;q+=256){
    int r=q>>7, i=q&127;
    s_rw[r][i]=read_w[((size_t)b*4+r)*1024 + i0+i];
    s_wr[r][i]=wwrw  [((size_t)b*4+r)*1024 + i0+i];
  }
  __syncthreads();
  float sa[4]={0,0,0,0}, sb[4]={0,0,0,0};
  const float* Lb = L + (size_t)b*1024*1024 + (size_t)i0*1024 + c;
  #pragma unroll 4
  for (int i=0;i<128;++i) {
    float lv = Lb[(size_t)i*1024];
    #pragma unroll
    for (int r=0;r<4;++r){ sa[r] += lv*s_rw[r][i]; sb[r] += lv*s_wr[r][i]; }
  }
  #pragma unroll
  for (int r=0;r<4;++r){
    SAp[(((size_t)(b*8+rc))*4+r)*1024 + c] = sa[r];
    SBp[(((size_t)(b*8+rc))*4+r)*1024 + c] = sb[r];
  }
}

// ---------------- K5: read content softmax + fwd/bwd combine -> new read weights ----------------
__global__ __launch_bounds__(256) void k_combine(
    const float* __restrict__ newmem, const float* __restrict__ invn,
    const float* __restrict__ rkn, const float* __restrict__ rs,
    const float* __restrict__ rm, const float* __restrict__ RA,
    const float* __restrict__ RB, const float* __restrict__ SAp,
    const float* __restrict__ SBp, const float* __restrict__ ww,
    const float* __restrict__ precedence, const float* __restrict__ read_w,
    const float* __restrict__ L, const float* __restrict__ prd,
    const float* __restrict__ wrd, float* __restrict__ nrw) {
  int b=blockIdx.x, r=blockIdx.y;
  int t=threadIdx.x, lane=t&63, wave=t>>6;
  __shared__ __align__(16) float s_key[64];
  __shared__ float s_sim[1024];
  __shared__ float s_red[4];
  __shared__ float s_bc[2];
  if (t<64) s_key[t]=rkn[((size_t)b*4+r)*64+t];
  __syncthreads();
  float rstr = rs[b*4+r];
  for (int n=t;n<1024;n+=256){
    const float4* row=(const float4*)(newmem + ((size_t)b*1024+n)*64);
    float dot=0.f;
    #pragma unroll
    for (int w4=0;w4<16;++w4) dot += dot4_(row[w4], ((const float4*)s_key)[w4]);
    s_sim[n]=dot*invn[b*1024+n]*rstr;
  }
  __syncthreads();
  { // softmax
    float lm=-1e30f;
    for (int n=t;n<1024;n+=256) lm=fmaxf(lm,s_sim[n]);
    for (int off=32;off;off>>=1) lm=fmaxf(lm,__shfl_xor(lm,off));
    if (lane==0) s_red[wave]=lm;
    __syncthreads();
    if (t==0) s_bc[0]=fmaxf(fmaxf(s_red[0],s_red[1]),fmaxf(s_red[2],s_red[3]));
    __syncthreads();
    float mx=s_bc[0], ls=0.f;
    for (int n=t;n<1024;n+=256){ float e=expf(s_sim[n]-mx); s_sim[n]=e; ls+=e; }
    for (int off=32;off;off>>=1) ls+=__shfl_xor(ls,off);
    if (lane==0) s_red[wave]=ls;
    __syncthreads();
    if (t==0) s_bc[1]=s_red[0]+s_red[1]+s_red[2]+s_red[3];
    __syncthreads();
    float inv=1.f/s_bc[1];
    for (int n=t;n<1024;n+=256) s_sim[n]*=inv;
  }
  __syncthreads();
  float m0=rm[b*12+r*3+0], m1=rm[b*12+r*3+1], m2=rm[b*12+r*3+2];
  float pd=prd[b*4+r], wd=wrd[b*4+r];
  for (int n=t;n<1024;n+=256) {
    float ra = RA[((size_t)b*4+r)*1024+n];
    float rb = RB[((size_t)b*4+r)*1024+n];
    float sa=0.f, sb=0.f;
    #pragma unroll
    for (int rc=0;rc<8;++rc){
      sa+=SAp[(((size_t)(b*8+rc))*4+r)*1024+n];
      sb+=SBp[(((size_t)(b*8+rc))*4+r)*1024+n];
    }
    float w_ = ww[b*1024+n];
    float pn = precedence[b*1024+n];
    float rwv= read_w[((size_t)b*4+r)*1024+n];
    float diag = L[(size_t)b*1048576 + (size_t)n*1025];
    float fwd = (1.f-w_)*ra - rb + w_*pd - ((1.f-2.f*w_)*diag + w_*pn)*rwv;
    float bwd = (1.f-w_)*sa - sb + pn*(wd - w_*rwv) - (1.f-2.f*w_)*diag*rwv;
    nrw[((size_t)b*4+r)*1024+n] = m0*bwd + m1*s_sim[n] + m2*fwd;
  }
}

// ---------------- K6: readout ----------------
__global__ __launch_bounds__(256) void k_readout(const float* __restrict__ nrw,
    const float* __restrict__ newmem, float* __restrict__ out){
  int b=blockIdx.x, r=blockIdx.y;
  int t=threadIdx.x, lane=t&63, g=t>>6;
  __shared__ float s_nrw[1024];
  __shared__ float s_part[4][64];
  for (int n=t;n<1024;n+=256) s_nrw[n]=nrw[((size_t)b*4+r)*1024+n];
  __syncthreads();
  float acc=0.f;
  for (int n=g;n<1024;n+=4) acc += s_nrw[n]*newmem[((size_t)b*1024+n)*64+lane];
  s_part[g][lane]=acc;
  __syncthreads();
  if (t<64) out[(b*4+r)*64+t] = s_part[0][t]+s_part[1][t]+s_part[2][t]+s_part[3][t];
}

extern "C" void kernel_launch(void* const* d_in, const int* in_sizes, int n_in,
                              void* d_out, int out_size, void* d_ws, size_t ws_size,
                              hipStream_t stream) {
  const float* x      = (const float*)d_in[0];
  const float* W_if   = (const float*)d_in[1];
  const float* b_if   = (const float*)d_in[2];
  const float* memory = (const float*)d_in[3];
  const float* link   = (const float*)d_in[4];
  const float* prec   = (const float*)d_in[5];
  const float* read_w = (const float*)d_in[6];
  const float* write_w= (const float*)d_in[7];
  const float* usage  = (const float*)d_in[8];
  float* out = (float*)d_out;
  float* ws = (float*)d_ws;

  float* xi   = ws + OFF_XI;
  float* rkn  = ws + OFF_RKN;
  float* rs   = ws + OFF_RS;
  float* er   = ws + OFF_ER;
  float* wv   = ws + OFF_WV;
  float* rm   = ws + OFF_RM;
  float* wwp  = ws + OFF_WW;
  float* wwrw = ws + OFF_WWRW;
  float* prd  = ws + OFF_PRD;
  float* wrd  = ws + OFF_WRD;
  float* invn = ws + OFF_INVN;
  float* nm   = ws + OFF_NM;
  float* RA   = ws + OFF_RA;
  float* RB   = ws + OFF_RB;
  float* SAp  = ws + OFF_SAP;
  float* SBp  = ws + OFF_SBP;
  float* nrw  = ws + OFF_NRW;

  k_xi<<<dim3(32,2), 256, 0, stream>>>(x, W_if, b_if, xi);
  k_batch<<<dim3(32), 256, 0, stream>>>(xi, memory, usage, read_w, write_w, prec,
                                        rkn, rs, er, wv, rm, wwp, wwrw, prd, wrd);
  k_newmem<<<dim3(32,256), 256, 0, stream>>>(memory, wwp, er, wv, nm, invn);
  k_fwd<<<dim3(32,32), 256, 0, stream>>>(link, read_w, wwrw, RA, RB);
  k_bwd<<<dim3(32,8,4), 256, 0, stream>>>(link, read_w, wwrw, SAp, SBp);
  k_combine<<<dim3(32,4), 256, 0, stream>>>(nm, invn, rkn, rs, rm, RA, RB, SAp, SBp,
                                            wwp, prec, read_w, link, prd, wrd, nrw);
  k_readout<<<dim3(32,4), 256, 0, stream>>>(nrw, nm, out);
}

// Round 3
// 393.222 us; speedup vs baseline: 1.0658x; 1.0658x over previous
//
#include <hip/hip_runtime.h>
#include <math.h>

#define DELTA_ 1e-6f
#define IFACE_ 471
#define XI_STRIDE 480

// workspace offsets (in floats)
#define OFF_XI    0            // 32*480
#define OFF_RKN   15360        // 32*4*64
#define OFF_RS    23552        // 32*4
#define OFF_ER    23680        // 32*64
#define OFF_WV    25728        // 32*64
#define OFF_RM    27776        // 32*12
#define OFF_WW    28160        // 32*1024
#define OFF_WWRW  60928        // 32*4*1024
#define OFF_PRD   192000       // 32*4
#define OFF_WRD   192128       // 32*4
#define OFF_INVN  192256       // 32*1024
#define OFF_DIAG  225024       // 32*1024
#define OFF_NM    257792       // 32*1024*64
#define OFF_RA    2354944      // 32*4*1024
#define OFF_RB    2486016      // 32*4*1024
#define OFF_SAP   2617088      // 32*16*4*1024
#define OFF_SBP   4714240     // 32*16*4*1024
// total 6811392 floats = 26 MB

__device__ __forceinline__ float sigm_(float x){ return 1.f/(1.f+expf(-x)); }
__device__ __forceinline__ float softp_(float x){ return fmaxf(x,0.f)+log1pf(expf(-fabsf(x))); }
__device__ __forceinline__ float dot4_(float4 a, float4 b){ return a.x*b.x+a.y*b.y+a.z*b.z+a.w*b.w; }

// ---------------- K1: xi = x @ W_if + b_if ----------------
// grid (32, 8): block covers 64 output cols, 4-way K split, LDS reduce.
__global__ __launch_bounds__(256) void k_xi(const float* __restrict__ x,
    const float* __restrict__ W, const float* __restrict__ bias,
    float* __restrict__ xi) {
  int b = blockIdx.x;
  int j0 = blockIdx.y*64;
  int t = threadIdx.x;
  int jl = t & 63, kq = t >> 6;
  __shared__ __align__(16) float sx[1024];
  __shared__ float s_part[256];
  for (int q=t; q<256; q+=256) ((float4*)sx)[q] = ((const float4*)(x + b*1024))[q];
  __syncthreads();
  int j = j0 + jl;
  int jc = j < IFACE_ ? j : IFACE_-1;
  float acc = 0.f;
  const float* Wp = W + (size_t)kq*256*IFACE_ + jc;
  #pragma unroll 4
  for (int k=0;k<256;++k) acc += sx[kq*256+k]*Wp[(size_t)k*IFACE_];
  s_part[t] = acc;
  __syncthreads();
  if (t < 64 && (j0+t) < IFACE_) {
    xi[b*XI_STRIDE + j0+t] = s_part[t]+s_part[64+t]+s_part[128+t]+s_part[192+t] + bias[j0+t];
  }
}

// ---------------- K2: per-batch: activations, wcw, usage, sort/alloc, ww ----------------
__global__ __launch_bounds__(256) void k_batch(
    const float* __restrict__ xi, const float* __restrict__ memory,
    const float* __restrict__ usage, const float* __restrict__ read_w,
    const float* __restrict__ write_w, const float* __restrict__ precedence,
    float* __restrict__ rkn, float* __restrict__ rs, float* __restrict__ er,
    float* __restrict__ wv, float* __restrict__ rm, float* __restrict__ ww_out,
    float* __restrict__ wwrw, float* __restrict__ prd, float* __restrict__ wrd) {
  int b = blockIdx.x; int t = threadIdx.x;
  int lane = t & 63; int wave = t >> 6;
  __shared__ float s_act[472];
  __shared__ __align__(16) float s_key[64];
  __shared__ float s_wcw[1024];
  __shared__ unsigned long long s_k64[1024];
  __shared__ float s_ps[1024];
  __shared__ float s_alloc[1024];
  __shared__ float s_red[32];
  __shared__ float s_bc[2];

  for (int q = t; q < IFACE_; q += 256) {
    float v = xi[b*XI_STRIDE+q];
    float a;
    if      (q < 256) a = tanhf(v);
    else if (q < 260) a = softp_(v);
    else if (q < 324) a = tanhf(v);
    else if (q < 325) a = softp_(v);
    else if (q < 389) a = sigm_(v);
    else if (q < 453) a = tanhf(v);
    else if (q < 459) a = sigm_(v);
    else              a = v;
    s_act[q] = a;
  }
  __syncthreads();
  if (t < 4) {
    float m0=s_act[459+3*t], m1=s_act[460+3*t], m2=s_act[461+3*t];
    float mx=fmaxf(m0,fmaxf(m1,m2));
    float e0=expf(m0-mx), e1=expf(m1-mx), e2=expf(m2-mx);
    float s=e0+e1+e2;
    rm[b*12+3*t+0]=e0/s; rm[b*12+3*t+1]=e1/s; rm[b*12+3*t+2]=e2/s;
  }
  if (t < 64) { er[b*64+t]=s_act[325+t]; wv[b*64+t]=s_act[389+t]; }
  {
    int r = wave;
    float v = s_act[r*64+lane];
    float ss = v*v;
    for (int off=32; off; off>>=1) ss += __shfl_xor(ss, off);
    rkn[((size_t)b*4+r)*64+lane] = v / (sqrtf(ss)+DELTA_);
    if (lane==0) rs[b*4+r] = s_act[256+r];
  }
  if (wave==0) {
    float v = s_act[260+lane];
    float ss=v*v;
    for (int off=32; off; off>>=1) ss += __shfl_xor(ss, off);
    s_key[lane] = v/(sqrtf(ss)+DELTA_);
  }
  __syncthreads();
  float wstr = s_act[324], agv = s_act[457], wgv = s_act[458];

  for (int n=t; n<1024; n+=256) {
    const float4* row = (const float4*)(memory + ((size_t)b*1024+n)*64);
    float dot=0.f, nn2=0.f;
    #pragma unroll
    for (int w4=0; w4<16; ++w4) {
      float4 m4 = row[w4];
      float4 k4 = ((const float4*)s_key)[w4];
      dot += dot4_(m4,k4);
      nn2 += dot4_(m4,m4);
    }
    s_wcw[n] = dot/(sqrtf(nn2)+DELTA_) * wstr;
  }
  __syncthreads();
  {
    float lm=-1e30f;
    for (int n=t;n<1024;n+=256) lm=fmaxf(lm,s_wcw[n]);
    for (int off=32;off;off>>=1) lm=fmaxf(lm,__shfl_xor(lm,off));
    if (lane==0) s_red[wave]=lm;
    __syncthreads();
    if (t==0) s_bc[0]=fmaxf(fmaxf(s_red[0],s_red[1]),fmaxf(s_red[2],s_red[3]));
    __syncthreads();
    float mx=s_bc[0], ls=0.f;
    for (int n=t;n<1024;n+=256){ float e=expf(s_wcw[n]-mx); s_wcw[n]=e; ls+=e; }
    for (int off=32;off;off>>=1) ls+=__shfl_xor(ls,off);
    if (lane==0) s_red[wave]=ls;
    __syncthreads();
    if (t==0) s_bc[1]=s_red[0]+s_red[1]+s_red[2]+s_red[3];
    __syncthreads();
    float inv=1.f/s_bc[1];
    for (int n=t;n<1024;n+=256) s_wcw[n]*=inv;
  }
  __syncthreads();

  for (int n=t; n<1024; n+=256) {
    float us = usage[b*1024+n];
    float wwi = write_w[b*1024+n];
    float u = us + (1.f-us)*wwi;
    float psi = 1.f;
    #pragma unroll
    for (int r=0;r<4;++r) psi *= (1.f - s_act[453+r]*read_w[((size_t)b*4+r)*1024+n]);
    u *= psi;
    u = DELTA_ + (1.f-DELTA_)*u;
    unsigned int ub = __float_as_uint(u);
    s_k64[n] = ((unsigned long long)ub<<32) | (unsigned int)n;
  }

  for (int k=2; k<=1024; k<<=1) {
    for (int j=k>>1; j>0; j>>=1) {
      __syncthreads();
      for (int idx=t; idx<1024; idx+=256) {
        int partner = idx ^ j;
        if (partner > idx) {
          unsigned long long a=s_k64[idx], c=s_k64[partner];
          bool asc = ((idx & k) == 0);
          bool sw = asc ? (a > c) : (a < c);
          if (sw) { s_k64[idx]=c; s_k64[partner]=a; }
        }
      }
    }
  }
  __syncthreads();

  for (int n=t;n<1024;n+=256) s_ps[n] = __uint_as_float((unsigned int)(s_k64[n]>>32));
  __syncthreads();
  for (int off=1; off<1024; off<<=1) {
    float tmp[4];
    #pragma unroll
    for (int m=0;m<4;++m){ int n=t+256*m; tmp[m] = (n>=off)? s_ps[n-off] : 1.f; }
    __syncthreads();
    #pragma unroll
    for (int m=0;m<4;++m){ int n=t+256*m; s_ps[n] *= tmp[m]; }
    __syncthreads();
  }
  for (int n=t;n<1024;n+=256) {
    unsigned long long kv = s_k64[n];
    float su = __uint_as_float((unsigned int)(kv>>32));
    int oi = (int)(kv & 0xffffffffu);
    float prod = (n==0)?1.f:s_ps[n-1];
    s_alloc[oi] = (1.f-su)*prod;
  }
  __syncthreads();

  float pp[4]={0,0,0,0}, wp[4]={0,0,0,0};
  for (int n=t;n<1024;n+=256) {
    float w_ = wgv*(agv*s_alloc[n] + (1.f-agv)*s_wcw[n]);
    ww_out[b*1024+n]=w_;
    float pn = precedence[b*1024+n];
    #pragma unroll
    for (int r=0;r<4;++r){
      float rwv = read_w[((size_t)b*4+r)*1024+n];
      wwrw[((size_t)b*4+r)*1024+n] = w_*rwv;
      pp[r] += pn*rwv;
      wp[r] += w_*rwv;
    }
  }
  #pragma unroll
  for (int r=0;r<4;++r){
    for (int off=32;off;off>>=1){ pp[r]+=__shfl_xor(pp[r],off); wp[r]+=__shfl_xor(wp[r],off); }
  }
  if (lane==0){
    #pragma unroll
    for (int r=0;r<4;++r){ s_red[wave*8+r]=pp[r]; s_red[wave*8+4+r]=wp[r]; }
  }
  __syncthreads();
  if (t<4)              prd[b*4+t]   = s_red[t]+s_red[8+t]+s_red[16+t]+s_red[24+t];
  else if (t<8){ int r=t-4; wrd[b*4+r] = s_red[4+r]+s_red[12+r]+s_red[20+r]+s_red[28+r]; }
}

// ---------------- K3: new memory + row inverse norms (float4) ----------------
// grid (32,16): block = 64 rows; thread = (row-of-16, lane16 of float4 cols)
__global__ __launch_bounds__(256) void k_newmem(const float* __restrict__ memory,
    const float* __restrict__ ww, const float* __restrict__ er,
    const float* __restrict__ wv, float* __restrict__ newmem, float* __restrict__ invn) {
  int b = blockIdx.x;
  int n0 = blockIdx.y*64;
  int t = threadIdx.x;
  int lane16 = t & 15, rl = t >> 4;
  __shared__ float s_ww[64];
  __shared__ __align__(16) float s_er[64];
  __shared__ __align__(16) float s_wv[64];
  if (t < 64) s_ww[t] = ww[b*1024 + n0 + t];
  else if (t < 128) s_er[t-64] = er[b*64 + (t-64)];
  else if (t < 192) s_wv[t-128] = wv[b*64 + (t-128)];
  __syncthreads();
  float4 e4 = ((const float4*)s_er)[lane16];
  float4 v4 = ((const float4*)s_wv)[lane16];
  #pragma unroll
  for (int p=0;p<4;++p) {
    int rloc = p*16 + rl;
    int row = n0 + rloc;
    float wn = s_ww[rloc];
    size_t i4 = ((size_t)b*1024+row)*16 + lane16;
    float4 m4 = ((const float4*)memory)[i4];
    float4 nv;
    nv.x = m4.x*(1.f-wn*e4.x) + wn*v4.x;
    nv.y = m4.y*(1.f-wn*e4.y) + wn*v4.y;
    nv.z = m4.z*(1.f-wn*e4.z) + wn*v4.z;
    nv.w = m4.w*(1.f-wn*e4.w) + wn*v4.w;
    ((float4*)newmem)[i4] = nv;
    float ss = dot4_(nv,nv);
    ss += __shfl_xor(ss,1); ss += __shfl_xor(ss,2);
    ss += __shfl_xor(ss,4); ss += __shfl_xor(ss,8);
    if (lane16==0) invn[b*1024+row] = 1.f/(sqrtf(ss)+DELTA_);
  }
}

// ---------------- K4a: row dots RA/RB ----------------
// grid (32,16): block = 64-row panel, all 1024 cols; wave owns 16 rows.
__global__ __launch_bounds__(256) void k_fwd(const float* __restrict__ L,
    const float* __restrict__ read_w, const float* __restrict__ wwrw,
    float* __restrict__ RA, float* __restrict__ RB) {
  int b = blockIdx.x;
  int i0 = blockIdx.y*64;
  __shared__ __align__(16) float4 s_rw[4][256];
  __shared__ __align__(16) float4 s_wr[4][256];
  for (int q=threadIdx.x; q<1024; q+=256) {
    int r=q>>8, c4=q&255;
    s_rw[r][c4] = ((const float4*)(read_w + ((size_t)b*4+r)*1024))[c4];
    s_wr[r][c4] = ((const float4*)(wwrw   + ((size_t)b*4+r)*1024))[c4];
  }
  __syncthreads();
  int wave=threadIdx.x>>6, lane=threadIdx.x&63;
  for (int qg=0; qg<4; ++qg) {
    int ib = i0 + wave*16 + qg*4;
    const float4* r0 = (const float4*)(L + ((size_t)b*1024 + ib+0)*1024);
    const float4* r1 = (const float4*)(L + ((size_t)b*1024 + ib+1)*1024);
    const float4* r2 = (const float4*)(L + ((size_t)b*1024 + ib+2)*1024);
    const float4* r3 = (const float4*)(L + ((size_t)b*1024 + ib+3)*1024);
    float acc[4][8];
    #pragma unroll
    for (int q=0;q<4;++q) for (int d=0;d<8;++d) acc[q][d]=0.f;
    #pragma unroll
    for (int m=0;m<4;++m){
      int c4 = lane + (m<<6);
      float4 l0=r0[c4], l1=r1[c4], l2=r2[c4], l3=r3[c4];
      #pragma unroll
      for (int r=0;r<4;++r){
        float4 rv=s_rw[r][c4], wv4=s_wr[r][c4];
        acc[0][r]+=dot4_(l0,rv); acc[0][r+4]+=dot4_(l0,wv4);
        acc[1][r]+=dot4_(l1,rv); acc[1][r+4]+=dot4_(l1,wv4);
        acc[2][r]+=dot4_(l2,rv); acc[2][r+4]+=dot4_(l2,wv4);
        acc[3][r]+=dot4_(l3,rv); acc[3][r+4]+=dot4_(l3,wv4);
      }
    }
    #pragma unroll
    for (int q=0;q<4;++q){
      #pragma unroll
      for (int d=0;d<8;++d){
        float v=acc[q][d];
        for (int off=32;off;off>>=1) v+=__shfl_xor(v,off);
        if (lane==0){
          int i = ib+q;
          if (d<4) RA[((size_t)b*4+d)*1024+i]=v;
          else     RB[((size_t)b*4+(d-4))*1024+i]=v;
        }
      }
    }
  }
}

// ---------------- K4b: col-sum partials SA/SB (float4) + diag extraction ----------------
// grid (32,16): block = 64-row panel x all 1024 cols; thread owns cols 4t..4t+3.
__global__ __launch_bounds__(256) void k_bwd(const float* __restrict__ L,
    const float* __restrict__ read_w, const float* __restrict__ wwrw,
    float* __restrict__ SAp, float* __restrict__ SBp, float* __restrict__ diag) {
  int b = blockIdx.x;
  int rc = blockIdx.y;
  int i0 = rc*64;
  int t = threadIdx.x;
  __shared__ float s_rw[4][64], s_wr[4][64];
  { int r = t>>6, i = t&63;
    s_rw[r][i]=read_w[((size_t)b*4+r)*1024 + i0+i];
    s_wr[r][i]=wwrw  [((size_t)b*4+r)*1024 + i0+i]; }
  __syncthreads();
  float4 sa0={0,0,0,0},sa1={0,0,0,0},sa2={0,0,0,0},sa3={0,0,0,0};
  float4 sb0={0,0,0,0},sb1={0,0,0,0},sb2={0,0,0,0},sb3={0,0,0,0};
  const float4* Lb = (const float4*)(L + (size_t)b*1048576 + (size_t)i0*1024);
  #pragma unroll 4
  for (int i=0;i<64;++i) {
    float4 lv = Lb[(size_t)i*256 + t];
    float w0=s_rw[0][i], w1=s_rw[1][i], w2=s_rw[2][i], w3=s_rw[3][i];
    float u0=s_wr[0][i], u1=s_wr[1][i], u2=s_wr[2][i], u3=s_wr[3][i];
    sa0.x+=lv.x*w0; sa0.y+=lv.y*w0; sa0.z+=lv.z*w0; sa0.w+=lv.w*w0;
    sa1.x+=lv.x*w1; sa1.y+=lv.y*w1; sa1.z+=lv.z*w1; sa1.w+=lv.w*w1;
    sa2.x+=lv.x*w2; sa2.y+=lv.y*w2; sa2.z+=lv.z*w2; sa2.w+=lv.w*w2;
    sa3.x+=lv.x*w3; sa3.y+=lv.y*w3; sa3.z+=lv.z*w3; sa3.w+=lv.w*w3;
    sb0.x+=lv.x*u0; sb0.y+=lv.y*u0; sb0.z+=lv.z*u0; sb0.w+=lv.w*u0;
    sb1.x+=lv.x*u1; sb1.y+=lv.y*u1; sb1.z+=lv.z*u1; sb1.w+=lv.w*u1;
    sb2.x+=lv.x*u2; sb2.y+=lv.y*u2; sb2.z+=lv.z*u2; sb2.w+=lv.w*u2;
    sb3.x+=lv.x*u3; sb3.y+=lv.y*u3; sb3.z+=lv.z*u3; sb3.w+=lv.w*u3;
    int idx = i0 + i;
    if ((idx>>2) == t) {
      int c = idx & 3;
      float d = (c==0)?lv.x:((c==1)?lv.y:((c==2)?lv.z:lv.w));
      diag[b*1024+idx] = d;
    }
  }
  size_t base = (((size_t)(b*16+rc))*4)*1024;
  ((float4*)(SAp + base          ))[t] = sa0;
  ((float4*)(SAp + base + 1024   ))[t] = sa1;
  ((float4*)(SAp + base + 2048   ))[t] = sa2;
  ((float4*)(SAp + base + 3072   ))[t] = sa3;
  ((float4*)(SBp + base          ))[t] = sb0;
  ((float4*)(SBp + base + 1024   ))[t] = sb1;
  ((float4*)(SBp + base + 2048   ))[t] = sb2;
  ((float4*)(SBp + base + 3072   ))[t] = sb3;
}

// ---------------- K5: content softmax + combine + readout (fused) ----------------
// grid (32,4): one block per (b, r)
__global__ __launch_bounds__(256) void k_read(
    const float* __restrict__ newmem, const float* __restrict__ invn,
    const float* __restrict__ rkn, const float* __restrict__ rs,
    const float* __restrict__ rm, const float* __restrict__ RA,
    const float* __restrict__ RB, const float* __restrict__ SAp,
    const float* __restrict__ SBp, const float* __restrict__ ww,
    const float* __restrict__ precedence, const float* __restrict__ read_w,
    const float* __restrict__ diag, const float* __restrict__ prd,
    const float* __restrict__ wrd, float* __restrict__ out) {
  int b=blockIdx.x, r=blockIdx.y;
  int t=threadIdx.x, lane=t&63, wave=t>>6;
  int lane16 = t & 15, rl = t >> 4;
  __shared__ __align__(16) float s_key[64];
  __shared__ float s_arr[1024];
  __shared__ float s_red[4];
  __shared__ float s_bc[2];
  __shared__ __align__(16) float4 s_acc[16][16];
  if (t<64) s_key[t]=rkn[((size_t)b*4+r)*64+t];
  __syncthreads();
  float rstr = rs[b*4+r];
  float4 key4 = ((const float4*)s_key)[lane16];
  // pass A: similarity scores
  for (int p=0;p<64;++p) {
    int row = p*16 + rl;
    float4 m4 = ((const float4*)newmem)[((size_t)b*1024+row)*16 + lane16];
    float d = dot4_(m4, key4);
    d += __shfl_xor(d,1); d += __shfl_xor(d,2);
    d += __shfl_xor(d,4); d += __shfl_xor(d,8);
    if (lane16==0) s_arr[row] = d * invn[b*1024+row] * rstr;
  }
  __syncthreads();
  { // softmax over s_arr
    float lm=-1e30f;
    for (int n=t;n<1024;n+=256) lm=fmaxf(lm,s_arr[n]);
    for (int off=32;off;off>>=1) lm=fmaxf(lm,__shfl_xor(lm,off));
    if (lane==0) s_red[wave]=lm;
    __syncthreads();
    if (t==0) s_bc[0]=fmaxf(fmaxf(s_red[0],s_red[1]),fmaxf(s_red[2],s_red[3]));
    __syncthreads();
    float mx=s_bc[0], ls=0.f;
    for (int n=t;n<1024;n+=256){ float e=expf(s_arr[n]-mx); s_arr[n]=e; ls+=e; }
    for (int off=32;off;off>>=1) ls+=__shfl_xor(ls,off);
    if (lane==0) s_red[wave]=ls;
    __syncthreads();
    if (t==0) s_bc[1]=s_red[0]+s_red[1]+s_red[2]+s_red[3];
    __syncthreads();
    float inv=1.f/s_bc[1];
    for (int n=t;n<1024;n+=256) s_arr[n]*=inv;
  }
  __syncthreads();
  float m0=rm[b*12+r*3+0], m1=rm[b*12+r*3+1], m2=rm[b*12+r*3+2];
  float pd=prd[b*4+r], wd=wrd[b*4+r];
  // nrw into s_arr
  for (int n=t;n<1024;n+=256) {
    float ra = RA[((size_t)b*4+r)*1024+n];
    float rb = RB[((size_t)b*4+r)*1024+n];
    float sa=0.f, sb=0.f;
    #pragma unroll
    for (int rc=0;rc<16;++rc){
      sa+=SAp[(((size_t)(b*16+rc))*4+r)*1024+n];
      sb+=SBp[(((size_t)(b*16+rc))*4+r)*1024+n];
    }
    float w_ = ww[b*1024+n];
    float pn = precedence[b*1024+n];
    float rwv= read_w[((size_t)b*4+r)*1024+n];
    float dg = diag[b*1024+n];
    float fwd = (1.f-w_)*ra - rb + w_*pd - ((1.f-2.f*w_)*dg + w_*pn)*rwv;
    float bwd = (1.f-w_)*sa - sb + pn*(wd - w_*rwv) - (1.f-2.f*w_)*dg*rwv;
    float crw = s_arr[n];
    __syncthreads();  // all reads of s_arr done before overwrite (uniform loop => safe)
    s_arr[n] = m0*bwd + m1*crw + m2*fwd;
    __syncthreads();
  }
  __syncthreads();
  // pass B: out[w] = sum_n nrw[n] * nm[n][w]
  float4 acc = {0,0,0,0};
  for (int p=0;p<64;++p) {
    int row = p*16 + rl;
    float4 m4 = ((const float4*)newmem)[((size_t)b*1024+row)*16 + lane16];
    float s = s_arr[row];
    acc.x += s*m4.x; acc.y += s*m4.y; acc.z += s*m4.z; acc.w += s*m4.w;
  }
  s_acc[rl][lane16] = acc;
  __syncthreads();
  if (t < 16) {
    float4 tot = {0,0,0,0};
    #pragma unroll
    for (int g=0; g<16; ++g) {
      float4 v = s_acc[g][t];
      tot.x+=v.x; tot.y+=v.y; tot.z+=v.z; tot.w+=v.w;
    }
    ((float4*)(out + (b*4+r)*64))[t] = tot;
  }
}

extern "C" void kernel_launch(void* const* d_in, const int* in_sizes, int n_in,
                              void* d_out, int out_size, void* d_ws, size_t ws_size,
                              hipStream_t stream) {
  const float* x      = (const float*)d_in[0];
  const float* W_if   = (const float*)d_in[1];
  const float* b_if   = (const float*)d_in[2];
  const float* memory = (const float*)d_in[3];
  const float* link   = (const float*)d_in[4];
  const float* prec   = (const float*)d_in[5];
  const float* read_w = (const float*)d_in[6];
  const float* write_w= (const float*)d_in[7];
  const float* usage  = (const float*)d_in[8];
  float* out = (float*)d_out;
  float* ws = (float*)d_ws;

  float* xi   = ws + OFF_XI;
  float* rkn  = ws + OFF_RKN;
  float* rs   = ws + OFF_RS;
  float* er   = ws + OFF_ER;
  float* wv   = ws + OFF_WV;
  float* rm   = ws + OFF_RM;
  float* wwp  = ws + OFF_WW;
  float* wwrw = ws + OFF_WWRW;
  float* prd  = ws + OFF_PRD;
  float* wrd  = ws + OFF_WRD;
  float* invn = ws + OFF_INVN;
  float* diag = ws + OFF_DIAG;
  float* nm   = ws + OFF_NM;
  float* RA   = ws + OFF_RA;
  float* RB   = ws + OFF_RB;
  float* SAp  = ws + OFF_SAP;
  float* SBp  = ws + OFF_SBP;

  k_xi<<<dim3(32,8), 256, 0, stream>>>(x, W_if, b_if, xi);
  k_batch<<<dim3(32), 256, 0, stream>>>(xi, memory, usage, read_w, write_w, prec,
                                        rkn, rs, er, wv, rm, wwp, wwrw, prd, wrd);
  k_newmem<<<dim3(32,16), 256, 0, stream>>>(memory, wwp, er, wv, nm, invn);
  k_fwd<<<dim3(32,16), 256, 0, stream>>>(link, read_w, wwrw, RA, RB);
  k_bwd<<<dim3(32,16), 256, 0, stream>>>(link, read_w, wwrw, SAp, SBp, diag);
  k_read<<<dim3(32,4), 256, 0, stream>>>(nm, invn, rkn, rs, rm, RA, RB, SAp, SBp,
                                         wwp, prec, read_w, diag, prd, wrd, out);
}